// Round 2
// baseline (171.387 us; speedup 1.0000x reference)
//
#include <hip/hip_runtime.h>
#include <cstdint>
#include <cstddef>

#define T_LEN 4096
#define S_DIM 308
#define E_DIM 126
#define NBATCH 32
#define NCHUNK 128
#define CHL 32
#define WARM 6     // contraction ~0.066/step -> ~1e-6 relative after warm-up
#define QSTR 336   // QL row stride (f16): 672B/row = 168 dw = 8 (mod 32) -> uniform b128

typedef _Float16 half8 __attribute__((ext_vector_type(8)));
typedef float floatx4 __attribute__((ext_vector_type(4)));

union HU8 { uint4 u; half8 h; };
union HU1 { uint16_t u; _Float16 h; };

__device__ __forceinline__ half8 h8_from_u4(uint4 v) { HU8 t; t.u = v; return t.h; }
__device__ __forceinline__ uint32_t pk2(float x, float y) {
  HU1 a, b; a.h = (_Float16)x; b.h = (_Float16)y;
  return (uint32_t)a.u | ((uint32_t)b.u << 16);
}

// ---- merged init: blocks 0..49 pack A-frags, 50..69 pack B-frags, 70 zeroes out ----
// A-frag: tile = nt*10 + kt; lane l holds A[k=kt*32+(l>>4)*8+j][n=nt*16+(l&15)], j=0..7.
// Serves as MFMA A-operand for P^T = A^T @ Q^T (m = out-state on l&15, k = in-state).
// B-frag: tile = nt*4 + kt over E padded to 128, value = 128*B[n][k]; MFMA A-operand
// for E^T = (128*Bmat) @ inp^T (m = state, k = e-dim). x128 telescopes into loglik.
__global__ __launch_bounds__(256) void init_pack(const float* __restrict__ A,
                                                 const float* __restrict__ Bm,
                                                 uint32_t* __restrict__ Apk,
                                                 uint32_t* __restrict__ Bfr,
                                                 float* __restrict__ out) {
  int blk = blockIdx.x, tid = threadIdx.x;
  if (blk < 50) {
    int idx = blk * 256 + tid;                 // 200 tiles * 64 lanes
    int lane = idx & 63, tile = idx >> 6;
    int kt = tile % 10, nt = tile / 10;
    int n  = nt * 16 + (lane & 15);
    int k0 = kt * 32 + (lane >> 4) * 8;
    uint32_t wv[4];
#pragma unroll
    for (int jj = 0; jj < 4; jj++) {
      int ka = k0 + 2 * jj, kb = ka + 1;
      float x0 = (n < S_DIM && ka < S_DIM) ? A[ka * S_DIM + n] : 0.f;
      float x1 = (n < S_DIM && kb < S_DIM) ? A[kb * S_DIM + n] : 0.f;
      wv[jj] = pk2(x0, x1);
    }
    uint4 o; o.x = wv[0]; o.y = wv[1]; o.z = wv[2]; o.w = wv[3];
    ((uint4*)Apk)[idx] = o;
  } else if (blk < 70) {
    int idx = (blk - 50) * 256 + tid;          // 80 tiles * 64 lanes
    int lane = idx & 63, tile = idx >> 6;
    int kt = tile % 4, nt = tile / 4;
    int n  = nt * 16 + (lane & 15);
    int k0 = kt * 32 + (lane >> 4) * 8;
    uint32_t wv[4];
#pragma unroll
    for (int jj = 0; jj < 4; jj++) {
      int ka = k0 + 2 * jj, kb = ka + 1;
      float x0 = (n < S_DIM && ka < E_DIM) ? 128.f * Bm[n * E_DIM + ka] : 0.f;
      float x1 = (n < S_DIM && kb < E_DIM) ? 128.f * Bm[n * E_DIM + kb] : 0.f;
      wv[jj] = pk2(x0, x1);
    }
    uint4 o; o.x = wv[0]; o.y = wv[1]; o.z = wv[2]; o.w = wv[3];
    ((uint4*)Bfr)[idx] = o;
  } else {
    if (tid < NBATCH) out[tid] = 0.f;
  }
}

// ---- fused recursion, round-4: balanced 4-wave, E fused in-register ----
// 256 thr = 4 waves x 5 state-tiles (1 wave/SIMD, perfectly balanced; 5-wave
// version had a 2-wave SIMD gating every barrier). A and 128*B live entirely in
// the unified VGPR/AGPR file (bfA 5x10, bfB 5x4 half8). No E materialization:
// each lane loads inp[b=gl][t][kt*32+quad*8..+8] (16x dwordx2, depth-2
// prefetch, L1-shared across waves) and 20 E-MFMAs produce E^T directly in the
// P/Q C-layout. E for step ii+1 is computed in phase b of step ii (E doesn't
// depend on P), filling the post-barrier QL ds_read latency with MFMA issue.
// Per step: a) qv = P (.) E; pack 4 states -> one ds_write_b64 per tile;
//           b) ONE barrier; E'(next) 20 MFMA + P = A^T Q^T 50 MFMA; reissue loads.
__global__ __launch_bounds__(256, 1)
void hmm_fused3(const uint32_t* __restrict__ Apk, const uint32_t* __restrict__ Bfr,
                const float* __restrict__ inp, const float* __restrict__ Ivec,
                float* __restrict__ out) {
  __shared__ __attribute__((aligned(16))) _Float16 QL[2][16 * QSTR];
  __shared__ float zslot[16];
  int c = blockIdx.x, bg = blockIdx.y, bbase = bg * 16;
  int tid = threadIdx.x, lane = tid & 63, w = tid >> 6;
  int gl = lane & 15, quad = lane >> 4, qoff = quad * 8;

  half8 bfA[5][10], bfB[5][4];
#pragma unroll
  for (int q = 0; q < 5; q++) {
#pragma unroll
    for (int kt = 0; kt < 10; kt++)
      bfA[q][kt] = h8_from_u4(((const uint4*)Apk)[((w * 5 + q) * 10 + kt) * 64 + lane]);
#pragma unroll
    for (int kt = 0; kt < 4; kt++)
      bfB[q][kt] = h8_from_u4(((const uint4*)Bfr)[((w * 5 + q) * 4 + kt) * 64 + lane]);
  }
#pragma unroll
  for (int q = 0; q < 5; q++) {
#pragma unroll
    for (int kt = 0; kt < 10; kt++) asm volatile("" : "+v"(bfA[q][kt]));
#pragma unroll
    for (int kt = 0; kt < 4; kt++)  asm volatile("" : "+v"(bfB[q][kt]));
  }

  // P init, state-major: lane holds states (w*5+q)*16 + quad*4 + r for batch gl
  float Pa[5][4];
#pragma unroll
  for (int q = 0; q < 5; q++) {
    int sb = (w * 5 + q) * 16 + quad * 4;
#pragma unroll
    for (int r = 0; r < 4; r++) {
      int s = sb + r;
      Pa[q][r] = (s < S_DIM) ? (c == 0 ? Ivec[s] : 1.0f) : 0.f;
    }
  }
  if (tid < 16) zslot[tid] = 0.f;

  int t_first = (c == 0) ? 1 : (c * CHL - WARM + 1);
  int nstep   = (c == 0) ? (CHL - 1) : (CHL + WARM - 1);   // 31 or 37 (both odd)
  int iw      = (c == 0) ? -1 : (WARM - 1);                // z at t = c*CHL-1
  int t_last  = t_first - 1 + nstep;

  // per-lane inp row base (batch = bbase+gl); rows are 8B-aligned (504B stride)
  const float* rowb = inp + (size_t)(bbase + gl) * T_LEN * E_DIM;

  float2 gA[4][4], gB[4][4];
  auto LOADG = [&](float2 (&G)[4][4], int t) {
    const float* p = rowb + (size_t)t * E_DIM;
#pragma unroll
    for (int kt = 0; kt < 4; kt++)
#pragma unroll
      for (int s = 0; s < 4; s++) {
        int e0 = kt * 32 + qoff + 2 * s;
        float2 v; v.x = 0.f; v.y = 0.f;
        if (e0 < E_DIM) v = *(const float2*)(p + e0);   // only (kt=3,quad=3,s=3) invalid
        G[kt][s] = v;
      }
  };
  auto CONV = [&](float2 (&G)[4][4], half8 (&h)[4]) {
#pragma unroll
    for (int kt = 0; kt < 4; kt++) {
      uint4 u;
      u.x = pk2(G[kt][0].x, G[kt][0].y);
      u.y = pk2(G[kt][1].x, G[kt][1].y);
      u.z = pk2(G[kt][2].x, G[kt][2].y);
      u.w = pk2(G[kt][3].x, G[kt][3].y);
      h[kt] = h8_from_u4(u);
    }
  };

  LOADG(gA, t_first - 1);
  LOADG(gB, t_first);

  // prologue: E for step 0 (t = t_first-1) from gA, then recycle gA <- t_first+1
  float Ea[5][4];
  {
    half8 h[4]; CONV(gA, h);
    floatx4 e0 = (floatx4){0.f,0.f,0.f,0.f}, e1 = e0, e2 = e0, e3 = e0, e4 = e0;
#pragma unroll
    for (int kt = 0; kt < 4; kt++) {
      e0 = __builtin_amdgcn_mfma_f32_16x16x32_f16(bfB[0][kt], h[kt], e0, 0, 0, 0);
      e1 = __builtin_amdgcn_mfma_f32_16x16x32_f16(bfB[1][kt], h[kt], e1, 0, 0, 0);
      e2 = __builtin_amdgcn_mfma_f32_16x16x32_f16(bfB[2][kt], h[kt], e2, 0, 0, 0);
      e3 = __builtin_amdgcn_mfma_f32_16x16x32_f16(bfB[3][kt], h[kt], e3, 0, 0, 0);
      e4 = __builtin_amdgcn_mfma_f32_16x16x32_f16(bfB[4][kt], h[kt], e4, 0, 0, 0);
    }
#pragma unroll
    for (int r = 0; r < 4; r++) {
      Ea[0][r] = e0[r]; Ea[1][r] = e1[r]; Ea[2][r] = e2[r]; Ea[3][r] = e3[r]; Ea[4][r] = e4[r];
    }
  }
  LOADG(gA, t_first + 1);

  float llw = 0.f;

  // step ii: uses Ea (= E at t_first-1+ii); phase b consumes G (inp at t_first+ii)
  // to build Ea for step ii+1, then reloads G <- t_first+ii+2.
  auto step = [&](float2 (&G)[4][4], int ii) {
    int cur = ii & 1;
    // ---- phase a: Q = P (.) E (registers only)
    float qv[5][4];
#pragma unroll
    for (int q = 0; q < 5; q++)
#pragma unroll
      for (int r = 0; r < 4; r++) qv[q][r] = Pa[q][r] * Ea[q][r];
    // checkpoints: z[b] = sum_s Q[s][b]
    if (ii == iw || ii == nstep) {
      float s = 0.f;
#pragma unroll
      for (int q = 0; q < 5; q++) s += (qv[q][0] + qv[q][1]) + (qv[q][2] + qv[q][3]);
      s += __shfl_xor(s, 16); s += __shfl_xor(s, 32);
      if (lane < 16) atomicAdd(&zslot[lane], s);
    }
    // write Q -> QL[cur]: 4 consecutive k-states per lane -> one b64 per tile
#pragma unroll
    for (int q = 0; q < 5; q++) {
      uint2 o;
      o.x = pk2(qv[q][0], qv[q][1]);
      o.y = pk2(qv[q][2], qv[q][3]);
      *(uint2*)&QL[cur][gl * QSTR + (w * 5 + q) * 16 + quad * 4] = o;
    }
    __syncthreads();   // the ONLY barrier per step
    if (ii == iw && tid < 16) { llw = logf(zslot[tid]); zslot[tid] = 0.f; }
    if (ii == nstep) {
      if (tid < 16) {
        float lle = logf(zslot[tid]);
        // CHL accounted steps between checkpoints, each carrying one x128
        atomicAdd(&out[bbase + tid], lle - llw - 32.0f * 4.852030263919617f);
      }
      return;
    }
    // ---- phase b: E(next) + P = A^T @ Q^T; E-MFMA issue hides QL read latency
    half8 h[4];
    CONV(G, h);
    {
      int tp = t_first + ii + 2; if (tp > t_last) tp = t_last;
      LOADG(G, tp);
    }
    floatx4 e0 = (floatx4){0.f,0.f,0.f,0.f}, e1 = e0, e2 = e0, e3 = e0, e4 = e0;
#pragma unroll
    for (int kt = 0; kt < 4; kt++) {
      e0 = __builtin_amdgcn_mfma_f32_16x16x32_f16(bfB[0][kt], h[kt], e0, 0, 0, 0);
      e1 = __builtin_amdgcn_mfma_f32_16x16x32_f16(bfB[1][kt], h[kt], e1, 0, 0, 0);
      e2 = __builtin_amdgcn_mfma_f32_16x16x32_f16(bfB[2][kt], h[kt], e2, 0, 0, 0);
      e3 = __builtin_amdgcn_mfma_f32_16x16x32_f16(bfB[3][kt], h[kt], e3, 0, 0, 0);
      e4 = __builtin_amdgcn_mfma_f32_16x16x32_f16(bfB[4][kt], h[kt], e4, 0, 0, 0);
    }
    floatx4 a0 = (floatx4){0.f,0.f,0.f,0.f}, a1 = a0, a2 = a0, a3 = a0, a4 = a0;
#pragma unroll
    for (int kt = 0; kt < 10; kt++) {
      half8 qf = h8_from_u4(*(const uint4*)&QL[cur][gl * QSTR + kt * 32 + qoff]);
      a0 = __builtin_amdgcn_mfma_f32_16x16x32_f16(bfA[0][kt], qf, a0, 0, 0, 0);
      a1 = __builtin_amdgcn_mfma_f32_16x16x32_f16(bfA[1][kt], qf, a1, 0, 0, 0);
      a2 = __builtin_amdgcn_mfma_f32_16x16x32_f16(bfA[2][kt], qf, a2, 0, 0, 0);
      a3 = __builtin_amdgcn_mfma_f32_16x16x32_f16(bfA[3][kt], qf, a3, 0, 0, 0);
      a4 = __builtin_amdgcn_mfma_f32_16x16x32_f16(bfA[4][kt], qf, a4, 0, 0, 0);
    }
#pragma unroll
    for (int r = 0; r < 4; r++) {
      Pa[0][r] = a0[r]; Pa[1][r] = a1[r]; Pa[2][r] = a2[r]; Pa[3][r] = a3[r]; Pa[4][r] = a4[r];
      Ea[0][r] = e0[r]; Ea[1][r] = e1[r]; Ea[2][r] = e2[r]; Ea[3][r] = e3[r]; Ea[4][r] = e4[r];
    }
  };

  // nstep is odd -> even number of sub-steps; gA/gB statically selected
  for (int i = 0; i <= nstep; i += 2) {
    step(gB, i);
    step(gA, i + 1);
  }
}

extern "C" void kernel_launch(void* const* d_in, const int* in_sizes, int n_in,
                              void* d_out, int out_size, void* d_ws, size_t ws_size,
                              hipStream_t stream) {
  const float* inp = (const float*)d_in[0];   // [32,4096,126]
  const float* A   = (const float*)d_in[1];   // [308,308]
  const float* Bm  = (const float*)d_in[2];   // [308,126]
  const float* Iv  = (const float*)d_in[3];   // [308]
  float* out = (float*)d_out;                 // [32]

  uint8_t* ws = (uint8_t*)d_ws;
  uint32_t* Apk = (uint32_t*)(ws);                 // 200 KiB
  uint32_t* Bfr = (uint32_t*)(ws + (256u << 10));  // 80 KiB

  hipLaunchKernelGGL(init_pack, dim3(71), dim3(256), 0, stream, A, Bm, Apk, Bfr, out);
  hipLaunchKernelGGL(hmm_fused3, dim3(NCHUNK, NBATCH / 16), dim3(256), 0, stream,
                     Apk, Bfr, inp, Iv, out);
}

// Round 3
// 162.005 us; speedup vs baseline: 1.0579x; 1.0579x over previous
//
#include <hip/hip_runtime.h>
#include <cstdint>
#include <cstddef>

#define T_LEN 4096
#define S_DIM 308
#define E_DIM 126
#define NBATCH 32
#define CHL 16                     // chunk length (was 32): 256 chunks, 2 per block
#define NCH (T_LEN / CHL)          // 256
#define WARM 6                     // contraction ~0.066/step -> ~1e-6 relative after warm-up
#define NSTEP (CHL + WARM - 1)     // 21, uniform for ALL chunks (c==0 uses reset-at-IW)
#define IW (WARM - 1)              // checkpoint substep (z at t = c*CHL-1)
#define QSTR 336                   // QL row stride (f16): 672B/row -> uniform b128 banks
#define TC 16                      // emis_pack timesteps per block
#define LN128 4.852030263919617f   // ln(128): per-step prescale to telescope out

typedef _Float16 half8 __attribute__((ext_vector_type(8)));
typedef _Float16 half4 __attribute__((ext_vector_type(4)));
typedef float floatx4 __attribute__((ext_vector_type(4)));

union HU8 { uint4 u; half8 h; };
union HU4 { uint2 u; half4 h; };
union HU1 { uint16_t u; _Float16 h; };

__device__ __forceinline__ half8 h8_from_u4(uint4 v) { HU8 t; t.u = v; return t.h; }
__device__ __forceinline__ half4 h4_from_u2(uint2 v) { HU4 t; t.u = v; return t.h; }
__device__ __forceinline__ uint32_t pk2(float x, float y) {
  HU1 a, b; a.h = (_Float16)x; b.h = (_Float16)y;
  return (uint32_t)a.u | ((uint32_t)b.u << 16);
}

// ---- merged init: blocks 0..49 pack A-frags, 50..69 pack B-frags, 70 zeroes out ----
// A-frag: tile = nt*10 + kt; lane l holds A[k=kt*32+(l>>4)*8+j][n=nt*16+(l&15)], j=0..7.
// Serves as MFMA A-operand for P^T = A^T @ Q^T (m = out-state, k = in-state).
// B-frag: tile = nt*4 + kt over E padded to 128, value = 128*B[n][k]; MFMA A-operand
// for E^T = (128*Bmat) @ inp^T in emis_pack. x128 telescopes into the loglik.
__global__ __launch_bounds__(256) void init_pack(const float* __restrict__ A,
                                                 const float* __restrict__ Bm,
                                                 uint32_t* __restrict__ Apk,
                                                 uint32_t* __restrict__ Bfr,
                                                 float* __restrict__ out) {
  int blk = blockIdx.x, tid = threadIdx.x;
  if (blk < 50) {
    int idx = blk * 256 + tid;                 // 200 tiles * 64 lanes
    int lane = idx & 63, tile = idx >> 6;
    int kt = tile % 10, nt = tile / 10;
    int n  = nt * 16 + (lane & 15);
    int k0 = kt * 32 + (lane >> 4) * 8;
    uint32_t wv[4];
#pragma unroll
    for (int jj = 0; jj < 4; jj++) {
      int ka = k0 + 2 * jj, kb = ka + 1;
      float x0 = (n < S_DIM && ka < S_DIM) ? A[ka * S_DIM + n] : 0.f;
      float x1 = (n < S_DIM && kb < S_DIM) ? A[kb * S_DIM + n] : 0.f;
      wv[jj] = pk2(x0, x1);
    }
    uint4 o; o.x = wv[0]; o.y = wv[1]; o.z = wv[2]; o.w = wv[3];
    ((uint4*)Apk)[idx] = o;
  } else if (blk < 70) {
    int idx = (blk - 50) * 256 + tid;          // 80 tiles * 64 lanes
    int lane = idx & 63, tile = idx >> 6;
    int kt = tile % 4, nt = tile / 4;
    int n  = nt * 16 + (lane & 15);
    int k0 = kt * 32 + (lane >> 4) * 8;
    uint32_t wv[4];
#pragma unroll
    for (int jj = 0; jj < 4; jj++) {
      int ka = k0 + 2 * jj, kb = ka + 1;
      float x0 = (n < S_DIM && ka < E_DIM) ? 128.f * Bm[n * E_DIM + ka] : 0.f;
      float x1 = (n < S_DIM && kb < E_DIM) ? 128.f * Bm[n * E_DIM + kb] : 0.f;
      wv[jj] = pk2(x0, x1);
    }
    uint4 o; o.x = wv[0]; o.y = wv[1]; o.z = wv[2]; o.w = wv[3];
    ((uint4*)Bfr)[idx] = o;
  } else {
    if (tid < NBATCH) out[tid] = 0.f;
  }
}

// ---- E precompute: E^T[t] fragments in main-loop register layout ----
// E^T = (128*Bmat) @ inp^T per t. Grid (T/TC, 2 batch-groups), 256 thr = 4 waves
// x 5 tiles. Lane packs its 4 f32 -> one uint2 at
// Efrag[(t*40 + bg*20 + nt)*64 + lane]  (512B fully-coalesced per wave-store).
__global__ __launch_bounds__(256, 2)
void emis_pack(const uint32_t* __restrict__ Bfr, const float* __restrict__ inp,
               uint2* __restrict__ Efrag) {
  __shared__ __attribute__((aligned(16))) _Float16 inH[2][16 * 136];
  int tc = blockIdx.x, bg = blockIdx.y, bbase = bg * 16;
  int tid = threadIdx.x, lane = tid & 63, w = tid >> 6;
  int gl = lane & 15, quad = lane >> 4;

  half8 bfB[5][4];
#pragma unroll
  for (int q = 0; q < 5; q++)
#pragma unroll
    for (int kt = 0; kt < 4; kt++)
      bfB[q][kt] = h8_from_u4(((const uint4*)Bfr)[((w * 5 + q) * 4 + kt) * 64 + lane]);
#pragma unroll
  for (int q = 0; q < 5; q++)
#pragma unroll
    for (int kt = 0; kt < 4; kt++) asm volatile("" : "+v"(bfB[q][kt]));

  int t0 = tc * TC;
#pragma unroll
  for (int s = 0; s < 4; s++) {
    int flat = tid + s * 256;
    int r = flat >> 6, c2 = flat & 63;
    float2 v; v.x = 0.f; v.y = 0.f;
    if (c2 < 63) v = *(const float2*)(inp + ((size_t)(bbase + r) * T_LEN + t0) * E_DIM + 2 * c2);
    *(uint32_t*)&inH[0][r * 136 + 2 * c2] = pk2(v.x, v.y);
  }
  float2 g[4];   // prefetch t0+1
#pragma unroll
  for (int s = 0; s < 4; s++) {
    int flat = tid + s * 256;
    int r = flat >> 6, c2 = flat & 63;
    g[s].x = 0.f; g[s].y = 0.f;
    if (c2 < 63) g[s] = *(const float2*)(inp + ((size_t)(bbase + r) * T_LEN + (t0 + 1)) * E_DIM + 2 * c2);
  }
  __syncthreads();

  for (int i = 0; i < TC; i++) {
    int cur = i & 1, t = t0 + i;
    floatx4 Ea[5];
#pragma unroll
    for (int q = 0; q < 5; q++) Ea[q] = (floatx4){0.f, 0.f, 0.f, 0.f};
#pragma unroll
    for (int kt = 0; kt < 4; kt++) {
      half8 af = h8_from_u4(*(const uint4*)&inH[cur][gl * 136 + kt * 32 + quad * 8]);
#pragma unroll
      for (int q = 0; q < 5; q++)
        Ea[q] = __builtin_amdgcn_mfma_f32_16x16x32_f16(bfB[q][kt], af, Ea[q], 0, 0, 0);
    }
    if (i < TC - 1) {
#pragma unroll
      for (int s = 0; s < 4; s++) {
        int flat = tid + s * 256;
        int r = flat >> 6, c2 = flat & 63;
        uint32_t pv = (c2 < 63) ? pk2(g[s].x, g[s].y) : 0u;
        *(uint32_t*)&inH[cur ^ 1][r * 136 + 2 * c2] = pv;
      }
      int tp = t0 + i + 2; if (tp > T_LEN - 1) tp = T_LEN - 1;
#pragma unroll
      for (int s = 0; s < 4; s++) {
        int flat = tid + s * 256;
        int r = flat >> 6, c2 = flat & 63;
        g[s].x = 0.f; g[s].y = 0.f;
        if (c2 < 63) g[s] = *(const float2*)(inp + ((size_t)(bbase + r) * T_LEN + tp) * E_DIM + 2 * c2);
      }
    }
#pragma unroll
    for (int q = 0; q < 5; q++) {
      uint2 o;
      o.x = pk2(Ea[q][0], Ea[q][1]);
      o.y = pk2(Ea[q][2], Ea[q][3]);
      Efrag[((size_t)t * 40 + bg * 20 + (w * 5 + q)) * 64 + lane] = o;
    }
    __syncthreads();
  }
}

// ---- fused recursion, round-5: DUAL-STREAM interleave ----
// Latency diagnosis: fused2 ran 2780 cyc/step vs 243 cyc MFMA-issue floor ->
// barrier/LDS/chain latency dominates with ~1 wave/SIMD (A-in-regs is too fat
// for a 2nd resident block). Fix: share the A registers between TWO independent
// time-chunks (2b, 2b+1) interleaved in one block. 256 thr = 4 waves x 5 tiles
// (balanced SIMDs). Per PAIR-step: phase a computes qv for both streams (pure
// VALU) + E prefetch; ONE barrier; phase b reads both QLs and issues 100 MFMAs
// over 10 independent chains -- each stream's latency hides under the other's
// issue. Barrier count per accounted step is HALVED. Chunk 0 runs the uniform
// warm schedule on garbage and does an exact reset Pa := I at substep IW.
__global__ __launch_bounds__(256, 1)
void hmm_fused4(const uint32_t* __restrict__ Apk, const uint2* __restrict__ Efrag,
                const float* __restrict__ Ivec, float* __restrict__ out) {
  __shared__ __attribute__((aligned(16))) _Float16 QL[2][2][16 * QSTR]; // [stream][buf]
  __shared__ float zslot[2][16];
  int bg = blockIdx.y, bbase = bg * 16;
  int cc0 = blockIdx.x * 2, cc1 = cc0 + 1;
  int tid = threadIdx.x, lane = tid & 63, w = tid >> 6;
  int gl = lane & 15, quad = lane >> 4, qoff = quad * 8;

  half8 bfA[5][10];
#pragma unroll
  for (int q = 0; q < 5; q++)
#pragma unroll
    for (int kt = 0; kt < 10; kt++)
      bfA[q][kt] = h8_from_u4(((const uint4*)Apk)[((w * 5 + q) * 10 + kt) * 64 + lane]);
#pragma unroll
  for (int q = 0; q < 5; q++)
#pragma unroll
    for (int kt = 0; kt < 10; kt++) asm volatile("" : "+v"(bfA[q][kt]));

  // P init, state-major: lane holds states (w*5+q)*16 + quad*4 + r for batch gl
  float Pa[2][5][4];
#pragma unroll
  for (int s = 0; s < 2; s++) {
    int cc = s ? cc1 : cc0;
#pragma unroll
    for (int q = 0; q < 5; q++) {
      int sb = (w * 5 + q) * 16 + quad * 4;
#pragma unroll
      for (int r = 0; r < 4; r++) {
        int st = sb + r;
        Pa[s][q][r] = (st < S_DIM) ? ((cc == 0) ? Ivec[st] : 1.0f) : 0.f;
      }
    }
  }
  if (tid < 32) zslot[tid >> 4][tid & 15] = 0.f;

  int tf[2] = { cc0 * CHL - WARM + 1, cc1 * CHL - WARM + 1 };   // may be <0 only for cc0==0
  int tl[2] = { tf[0] + NSTEP - 1, tf[1] + NSTEP - 1 };

  size_t ebase = (size_t)bg * 1280 + (size_t)(w * 5) * 64 + lane;

  uint2 EA[2][5], EB[2][5];
#pragma unroll
  for (int s = 0; s < 2; s++) {
    int ta = tf[s] - 1; if (ta < 0) ta = 0;
    int tb = tf[s];     if (tb < 0) tb = 0;
#pragma unroll
    for (int q = 0; q < 5; q++) {
      EA[s][q] = Efrag[(size_t)ta * 2560 + ebase + (size_t)q * 64];
      EB[s][q] = Efrag[(size_t)tb * 2560 + ebase + (size_t)q * 64];
    }
  }

  float llw0 = 0.f, llw1 = 0.f;

  auto step = [&](uint2 (&E)[2][5], int ii) {
    int cur = ii & 1;
    // ---- phase a: Q = P (.) E, both streams (registers only)
    float qv[2][5][4];
#pragma unroll
    for (int s = 0; s < 2; s++)
#pragma unroll
      for (int q = 0; q < 5; q++) {
        half4 ev = h4_from_u2(E[s][q]);
#pragma unroll
        for (int r = 0; r < 4; r++) qv[s][q][r] = Pa[s][q][r] * (float)ev[r];
      }
    // prefetch E(t+2) into the just-consumed buffer
#pragma unroll
    for (int s = 0; s < 2; s++) {
      int tp = tf[s] + ii + 1;
      if (tp < 0) tp = 0;
      if (tp > tl[s]) tp = tl[s];
#pragma unroll
      for (int q = 0; q < 5; q++)
        E[s][q] = Efrag[(size_t)tp * 2560 + ebase + (size_t)q * 64];
    }
    // checkpoints: z[b] = sum_s Q[s][b]
    if (ii == IW || ii == NSTEP) {
#pragma unroll
      for (int s = 0; s < 2; s++) {
        float z = 0.f;
#pragma unroll
        for (int q = 0; q < 5; q++) z += (qv[s][q][0] + qv[s][q][1]) + (qv[s][q][2] + qv[s][q][3]);
        z += __shfl_xor(z, 16); z += __shfl_xor(z, 32);
        if (lane < 16) atomicAdd(&zslot[s][lane], z);
      }
    }
    // write Q -> QL[s][cur]: 4 consecutive k-states per lane -> one b64 per tile
#pragma unroll
    for (int s = 0; s < 2; s++)
#pragma unroll
      for (int q = 0; q < 5; q++) {
        uint2 o;
        o.x = pk2(qv[s][q][0], qv[s][q][1]);
        o.y = pk2(qv[s][q][2], qv[s][q][3]);
        *(uint2*)&QL[s][cur][gl * QSTR + (w * 5 + q) * 16 + quad * 4] = o;
      }
    __syncthreads();   // the ONLY barrier per pair-step
    if (ii == IW) {
      if (tid < 16) {
        if (cc0 != 0) llw0 = logf(zslot[0][tid]);     // cc0==0: garbage warm, llw stays 0
        llw1 = logf(zslot[1][tid]);                   // cc1 >= 1 always
        zslot[0][tid] = 0.f; zslot[1][tid] = 0.f;
      }
    }
    if (ii == NSTEP) {
      if (tid < 16) {
        float v = (logf(zslot[0][tid]) - llw0) + (logf(zslot[1][tid]) - llw1)
                  - 2.0f * (float)CHL * LN128;        // CHL steps/stream, x128 each
        atomicAdd(&out[bbase + tid], v);
      }
      return;
    }
    // ---- phase b: P^T = A^T @ Q^T, both streams (10 independent MFMA chains)
    floatx4 a[2][5];
#pragma unroll
    for (int s = 0; s < 2; s++)
#pragma unroll
      for (int q = 0; q < 5; q++) a[s][q] = (floatx4){0.f, 0.f, 0.f, 0.f};
#pragma unroll
    for (int kt = 0; kt < 10; kt++) {
      half8 q0 = h8_from_u4(*(const uint4*)&QL[0][cur][gl * QSTR + kt * 32 + qoff]);
      half8 q1 = h8_from_u4(*(const uint4*)&QL[1][cur][gl * QSTR + kt * 32 + qoff]);
#pragma unroll
      for (int q = 0; q < 5; q++) {
        a[0][q] = __builtin_amdgcn_mfma_f32_16x16x32_f16(bfA[q][kt], q0, a[0][q], 0, 0, 0);
        a[1][q] = __builtin_amdgcn_mfma_f32_16x16x32_f16(bfA[q][kt], q1, a[1][q], 0, 0, 0);
      }
    }
#pragma unroll
    for (int s = 0; s < 2; s++)
#pragma unroll
      for (int q = 0; q < 5; q++)
#pragma unroll
        for (int r = 0; r < 4; r++) Pa[s][q][r] = a[s][q][r];
    if (ii == IW && cc0 == 0) {
      // exact restart of chunk 0 at t=0: Pa := I (its phase-a at IW+1 uses E(0))
#pragma unroll
      for (int q = 0; q < 5; q++) {
        int sb = (w * 5 + q) * 16 + quad * 4;
#pragma unroll
        for (int r = 0; r < 4; r++) {
          int st = sb + r;
          Pa[0][q][r] = (st < S_DIM) ? Ivec[st] : 0.f;
        }
      }
    }
  };

  // NSTEP odd -> even number of sub-steps; EA/EB statically selected
  for (int i = 0; i <= NSTEP; i += 2) {
    step(EA, i);
    step(EB, i + 1);
  }
}

// ---- fallback (inp-direct, no Efrag workspace) ----
__global__ __launch_bounds__(640, 3)
void hmm_fused(const uint32_t* __restrict__ Apk,
               const uint32_t* __restrict__ Bfr,
               const float* __restrict__ inp,
               const float* __restrict__ Ivec,
               float* __restrict__ out) {
  __shared__ __attribute__((aligned(16))) _Float16 inH[2][16 * 136];
  __shared__ __attribute__((aligned(16))) _Float16 QLf[2][16 * QSTR];
  __shared__ float zslot[16];
  int c = blockIdx.x, bbase = blockIdx.y * 16;
  int tid = threadIdx.x, lane = tid & 63, w = tid >> 6;
  int gl = lane & 15, quad = lane >> 4;

  half8 bfA[2][10], bfB[2][4];
#pragma unroll
  for (int q = 0; q < 2; q++) {
#pragma unroll
    for (int kt = 0; kt < 10; kt++)
      bfA[q][kt] = h8_from_u4(((const uint4*)Apk)[((w * 2 + q) * 10 + kt) * 64 + lane]);
#pragma unroll
    for (int kt = 0; kt < 4; kt++)
      bfB[q][kt] = h8_from_u4(((const uint4*)Bfr)[((w * 2 + q) * 4 + kt) * 64 + lane]);
  }
#pragma unroll
  for (int q = 0; q < 2; q++) {
#pragma unroll
    for (int kt = 0; kt < 10; kt++) asm volatile("" : "+v"(bfA[q][kt]));
#pragma unroll
    for (int kt = 0; kt < 4; kt++)  asm volatile("" : "+v"(bfB[q][kt]));
  }

  float Pa[2][4];
#pragma unroll
  for (int q = 0; q < 2; q++) {
    int n = (w * 2 + q) * 16 + gl;
    float v = (n < S_DIM) ? (c == 0 ? Ivec[n] : 1.0f) : 0.f;
#pragma unroll
    for (int r = 0; r < 4; r++) Pa[q][r] = v;
  }
  if (tid < 16) zslot[tid] = 0.f;

  int t_first = (c == 0) ? 1 : (c * CHL - WARM + 1);
  int nstep   = (c == 0) ? (CHL - 1) : (CHL + WARM - 1);
  int iw      = (c == 0) ? -1 : (WARM - 1);
  int t_last  = t_first - 1 + nstep;

  {
    int t0 = t_first - 1;
#pragma unroll
    for (int s = 0; s < 2; s++) {
      int flat = tid + s * 640;
      if (flat < 1024) {
        int r = flat >> 6, c2 = flat & 63;
        float2 v; v.x = 0.f; v.y = 0.f;
        if (c2 < 63) v = *(const float2*)(inp + ((size_t)(bbase + r) * T_LEN + t0) * E_DIM + 2 * c2);
        *(uint32_t*)&inH[0][r * 136 + 2 * c2] = pk2(v.x, v.y);
      }
    }
  }
  float2 g[2];
#pragma unroll
  for (int s = 0; s < 2; s++) {
    int flat = tid + s * 640;
    g[s].x = 0.f; g[s].y = 0.f;
    if (flat < 1024) {
      int r = flat >> 6, c2 = flat & 63;
      if (c2 < 63) g[s] = *(const float2*)(inp + ((size_t)(bbase + r) * T_LEN + t_first) * E_DIM + 2 * c2);
    }
  }
  float llw = 0.f;
  __syncthreads();

  for (int i = 0; i <= nstep; i++) {
    int cur = i & 1, nxt = cur ^ 1;
    floatx4 Ea0 = (floatx4){0.f, 0.f, 0.f, 0.f};
    floatx4 Ea1 = (floatx4){0.f, 0.f, 0.f, 0.f};
#pragma unroll
    for (int kt = 0; kt < 4; kt++) {
      half8 af = h8_from_u4(*(const uint4*)&inH[cur][gl * 136 + kt * 32 + quad * 8]);
      Ea0 = __builtin_amdgcn_mfma_f32_16x16x32_f16(af, bfB[0][kt], Ea0, 0, 0, 0);
      Ea1 = __builtin_amdgcn_mfma_f32_16x16x32_f16(af, bfB[1][kt], Ea1, 0, 0, 0);
    }
    float qv[2][4];
#pragma unroll
    for (int r = 0; r < 4; r++) { qv[0][r] = Pa[0][r] * Ea0[r]; qv[1][r] = Pa[1][r] * Ea1[r]; }
    if (i == iw || i == nstep) {
      float s0 = qv[0][0] + qv[1][0], s1 = qv[0][1] + qv[1][1];
      float s2 = qv[0][2] + qv[1][2], s3 = qv[0][3] + qv[1][3];
#pragma unroll
      for (int off = 1; off <= 8; off <<= 1) {
        s0 += __shfl_xor(s0, off); s1 += __shfl_xor(s1, off);
        s2 += __shfl_xor(s2, off); s3 += __shfl_xor(s3, off);
      }
      if (gl == 0) {
        atomicAdd(&zslot[quad * 4 + 0], s0);
        atomicAdd(&zslot[quad * 4 + 1], s1);
        atomicAdd(&zslot[quad * 4 + 2], s2);
        atomicAdd(&zslot[quad * 4 + 3], s3);
      }
    }
#pragma unroll
    for (int q = 0; q < 2; q++) {
      int k = (w * 2 + q) * 16 + gl;
#pragma unroll
      for (int r = 0; r < 4; r++)
        QLf[cur][(quad * 4 + r) * QSTR + k] = (_Float16)qv[q][r];
    }
    if (i < nstep) {
#pragma unroll
      for (int s = 0; s < 2; s++) {
        int flat = tid + s * 640;
        if (flat < 1024) {
          int r = flat >> 6, c2 = flat & 63;
          uint32_t pv = (c2 < 63) ? pk2(g[s].x, g[s].y) : 0u;
          *(uint32_t*)&inH[nxt][r * 136 + 2 * c2] = pv;
        }
      }
    }
    __syncthreads();
    if (i == iw && tid < 16) { llw = logf(zslot[tid]); zslot[tid] = 0.f; }
    if (i == nstep) {
      if (tid < 16) {
        float lle = logf(zslot[tid]);
        atomicAdd(&out[bbase + tid], lle - llw - (float)CHL * LN128);
      }
      break;
    }
    {
      int tp = t_first + i + 1; if (tp > t_last) tp = t_last;
#pragma unroll
      for (int s = 0; s < 2; s++) {
        int flat = tid + s * 640;
        g[s].x = 0.f; g[s].y = 0.f;
        if (flat < 1024) {
          int r = flat >> 6, c2 = flat & 63;
          if (c2 < 63) g[s] = *(const float2*)(inp + ((size_t)(bbase + r) * T_LEN + tp) * E_DIM + 2 * c2);
        }
      }
    }
    floatx4 acc0 = (floatx4){0.f, 0.f, 0.f, 0.f};
    floatx4 acc1 = (floatx4){0.f, 0.f, 0.f, 0.f};
#pragma unroll
    for (int kt = 0; kt < 10; kt++) {
      half8 afv = h8_from_u4(*(const uint4*)&QLf[cur][gl * QSTR + kt * 32 + quad * 8]);
      acc0 = __builtin_amdgcn_mfma_f32_16x16x32_f16(afv, bfA[0][kt], acc0, 0, 0, 0);
      acc1 = __builtin_amdgcn_mfma_f32_16x16x32_f16(afv, bfA[1][kt], acc1, 0, 0, 0);
    }
#pragma unroll
    for (int r = 0; r < 4; r++) { Pa[0][r] = acc0[r]; Pa[1][r] = acc1[r]; }
  }
}

extern "C" void kernel_launch(void* const* d_in, const int* in_sizes, int n_in,
                              void* d_out, int out_size, void* d_ws, size_t ws_size,
                              hipStream_t stream) {
  const float* inp = (const float*)d_in[0];   // [32,4096,126]
  const float* A   = (const float*)d_in[1];   // [308,308]
  const float* Bm  = (const float*)d_in[2];   // [308,126]
  const float* Iv  = (const float*)d_in[3];   // [308]
  float* out = (float*)d_out;                 // [32]

  uint8_t* ws = (uint8_t*)d_ws;
  uint32_t* Apk = (uint32_t*)(ws);                 // 200 KiB
  uint32_t* Bfr = (uint32_t*)(ws + (256u << 10));  // 80 KiB
  const size_t EOFF   = (size_t)384 << 10;
  const size_t EBYTES = (size_t)T_LEN * 40 * 64 * sizeof(uint2);  // 80 MiB

  hipLaunchKernelGGL(init_pack, dim3(71), dim3(256), 0, stream, A, Bm, Apk, Bfr, out);
  if (ws_size >= EOFF + EBYTES) {
    uint2* Efrag = (uint2*)(ws + EOFF);
    hipLaunchKernelGGL(emis_pack, dim3(T_LEN / TC, 2), dim3(256), 0, stream, Bfr, inp, Efrag);
    hipLaunchKernelGGL(hmm_fused4, dim3(NCH / 2, NBATCH / 16), dim3(256), 0, stream,
                       Apk, Efrag, Iv, out);
  } else {
    hipLaunchKernelGGL(hmm_fused, dim3(NCH, NBATCH / 16), dim3(640), 0, stream,
                       Apk, Bfr, inp, Iv, out);
  }
}

// Round 4
// 160.603 us; speedup vs baseline: 1.0671x; 1.0087x over previous
//
#include <hip/hip_runtime.h>
#include <cstdint>
#include <cstddef>

#define T_LEN 4096
#define S_DIM 308
#define E_DIM 126
#define NBATCH 32
#define CHL 16                     // chunk length: 256 chunks, 2 per block (skewed)
#define NCH (T_LEN / CHL)          // 256
#define WARM 6                     // contraction ~0.066/step -> ~1e-6 relative after warm-up
#define NSTEP (CHL + WARM - 1)     // 21, uniform for ALL chunks (c==0 uses reset-at-IW)
#define IW (WARM - 1)              // checkpoint substep (z at t = c*CHL-1)
#define QROW 720                   // QL row stride BYTES = 180 dw == 20 (mod 32):
                                   //   b128 reads 8/bank, b64 writes 4/bank = conflict-free
#define TC 16                      // emis_pack timesteps per block
#define ROWB 20480                 // Efrag row bytes: 40 tiles * 64 lanes * 8B
#define LN128 4.852030263919617f   // ln(128): per-step prescale to telescope out

typedef _Float16 half8 __attribute__((ext_vector_type(8)));
typedef _Float16 half4 __attribute__((ext_vector_type(4)));
typedef float floatx4 __attribute__((ext_vector_type(4)));

union HU8 { uint4 u; half8 h; };
union HU4 { uint2 u; half4 h; };
union HU1 { uint16_t u; _Float16 h; };

__device__ __forceinline__ half8 h8_from_u4(uint4 v) { HU8 t; t.u = v; return t.h; }
__device__ __forceinline__ half4 h4_from_u2(uint2 v) { HU4 t; t.u = v; return t.h; }
__device__ __forceinline__ uint32_t pk2(float x, float y) {
  HU1 a, b; a.h = (_Float16)x; b.h = (_Float16)y;
  return (uint32_t)a.u | ((uint32_t)b.u << 16);
}

// ---- merged init: blocks 0..49 pack A-frags, 50..69 pack B-frags, 70 zeroes out ----
// A-frag: tile = nt*10 + kt; lane l holds A[k=kt*32+(l>>4)*8+j][n=nt*16+(l&15)], j=0..7.
// Serves as MFMA A-operand for P^T = A^T @ Q^T (m = out-state, k = in-state).
// B-frag: tile = nt*4 + kt over E padded to 128, value = 128*B[n][k]; MFMA A-operand
// for E^T = (128*Bmat) @ inp^T in emis_pack. x128 telescopes into the loglik.
__global__ __launch_bounds__(256) void init_pack(const float* __restrict__ A,
                                                 const float* __restrict__ Bm,
                                                 uint32_t* __restrict__ Apk,
                                                 uint32_t* __restrict__ Bfr,
                                                 float* __restrict__ out) {
  int blk = blockIdx.x, tid = threadIdx.x;
  if (blk < 50) {
    int idx = blk * 256 + tid;                 // 200 tiles * 64 lanes
    int lane = idx & 63, tile = idx >> 6;
    int kt = tile % 10, nt = tile / 10;
    int n  = nt * 16 + (lane & 15);
    int k0 = kt * 32 + (lane >> 4) * 8;
    uint32_t wv[4];
#pragma unroll
    for (int jj = 0; jj < 4; jj++) {
      int ka = k0 + 2 * jj, kb = ka + 1;
      float x0 = (n < S_DIM && ka < S_DIM) ? A[ka * S_DIM + n] : 0.f;
      float x1 = (n < S_DIM && kb < S_DIM) ? A[kb * S_DIM + n] : 0.f;
      wv[jj] = pk2(x0, x1);
    }
    uint4 o; o.x = wv[0]; o.y = wv[1]; o.z = wv[2]; o.w = wv[3];
    ((uint4*)Apk)[idx] = o;
  } else if (blk < 70) {
    int idx = (blk - 50) * 256 + tid;          // 80 tiles * 64 lanes
    int lane = idx & 63, tile = idx >> 6;
    int kt = tile % 4, nt = tile / 4;
    int n  = nt * 16 + (lane & 15);
    int k0 = kt * 32 + (lane >> 4) * 8;
    uint32_t wv[4];
#pragma unroll
    for (int jj = 0; jj < 4; jj++) {
      int ka = k0 + 2 * jj, kb = ka + 1;
      float x0 = (n < S_DIM && ka < E_DIM) ? 128.f * Bm[n * E_DIM + ka] : 0.f;
      float x1 = (n < S_DIM && kb < E_DIM) ? 128.f * Bm[n * E_DIM + kb] : 0.f;
      wv[jj] = pk2(x0, x1);
    }
    uint4 o; o.x = wv[0]; o.y = wv[1]; o.z = wv[2]; o.w = wv[3];
    ((uint4*)Bfr)[idx] = o;
  } else {
    if (tid < NBATCH) out[tid] = 0.f;
  }
}

// ---- E precompute: E^T[t] fragments in main-loop register layout ----
// E^T = (128*Bmat) @ inp^T per t. Grid (T/TC, 2 batch-groups), 256 thr = 4 waves
// x 5 tiles. Lane packs its 4 f32 -> one uint2 at
// Efrag[(t*40 + bg*20 + nt)*64 + lane]  (512B fully-coalesced per wave-store).
__global__ __launch_bounds__(256, 2)
void emis_pack(const uint32_t* __restrict__ Bfr, const float* __restrict__ inp,
               uint2* __restrict__ Efrag) {
  __shared__ __attribute__((aligned(16))) _Float16 inH[2][16 * 136];
  int tc = blockIdx.x, bg = blockIdx.y, bbase = bg * 16;
  int tid = threadIdx.x, lane = tid & 63, w = tid >> 6;
  int gl = lane & 15, quad = lane >> 4;

  half8 bfB[5][4];
#pragma unroll
  for (int q = 0; q < 5; q++)
#pragma unroll
    for (int kt = 0; kt < 4; kt++)
      bfB[q][kt] = h8_from_u4(((const uint4*)Bfr)[((w * 5 + q) * 4 + kt) * 64 + lane]);
#pragma unroll
  for (int q = 0; q < 5; q++)
#pragma unroll
    for (int kt = 0; kt < 4; kt++) asm volatile("" : "+v"(bfB[q][kt]));

  int t0 = tc * TC;
#pragma unroll
  for (int s = 0; s < 4; s++) {
    int flat = tid + s * 256;
    int r = flat >> 6, c2 = flat & 63;
    float2 v; v.x = 0.f; v.y = 0.f;
    if (c2 < 63) v = *(const float2*)(inp + ((size_t)(bbase + r) * T_LEN + t0) * E_DIM + 2 * c2);
    *(uint32_t*)&inH[0][r * 136 + 2 * c2] = pk2(v.x, v.y);
  }
  float2 g[4];   // prefetch t0+1
#pragma unroll
  for (int s = 0; s < 4; s++) {
    int flat = tid + s * 256;
    int r = flat >> 6, c2 = flat & 63;
    g[s].x = 0.f; g[s].y = 0.f;
    if (c2 < 63) g[s] = *(const float2*)(inp + ((size_t)(bbase + r) * T_LEN + (t0 + 1)) * E_DIM + 2 * c2);
  }
  __syncthreads();

  for (int i = 0; i < TC; i++) {
    int cur = i & 1, t = t0 + i;
    floatx4 Ea[5];
#pragma unroll
    for (int q = 0; q < 5; q++) Ea[q] = (floatx4){0.f, 0.f, 0.f, 0.f};
#pragma unroll
    for (int kt = 0; kt < 4; kt++) {
      half8 af = h8_from_u4(*(const uint4*)&inH[cur][gl * 136 + kt * 32 + quad * 8]);
#pragma unroll
      for (int q = 0; q < 5; q++)
        Ea[q] = __builtin_amdgcn_mfma_f32_16x16x32_f16(bfB[q][kt], af, Ea[q], 0, 0, 0);
    }
    if (i < TC - 1) {
#pragma unroll
      for (int s = 0; s < 4; s++) {
        int flat = tid + s * 256;
        int r = flat >> 6, c2 = flat & 63;
        uint32_t pv = (c2 < 63) ? pk2(g[s].x, g[s].y) : 0u;
        *(uint32_t*)&inH[cur ^ 1][r * 136 + 2 * c2] = pv;
      }
      int tp = t0 + i + 2; if (tp > T_LEN - 1) tp = T_LEN - 1;
#pragma unroll
      for (int s = 0; s < 4; s++) {
        int flat = tid + s * 256;
        int r = flat >> 6, c2 = flat & 63;
        g[s].x = 0.f; g[s].y = 0.f;
        if (c2 < 63) g[s] = *(const float2*)(inp + ((size_t)(bbase + r) * T_LEN + tp) * E_DIM + 2 * c2);
      }
    }
#pragma unroll
    for (int q = 0; q < 5; q++) {
      uint2 o;
      o.x = pk2(Ea[q][0], Ea[q][1]);
      o.y = pk2(Ea[q][2], Ea[q][3]);
      Efrag[((size_t)t * 40 + bg * 20 + (w * 5 + q)) * 64 + lane] = o;
    }
    __syncthreads();
  }
}

// ---- fused recursion, round-6: PHASE-SKEWED dual-stream ----
// Round-3 lesson: lockstep dual-stream = 2x serial work, zero overlap. Skew
// instead: each barrier interval pairs phase-a(stream s) with phase-b(other):
//   half 2k  : aY(k) writes QL_Y  ||  bX(k) reads QL_X + 50 MFMA + E-prefetch X
//   half 2k+1: aX(k+1) writes QL_X ||  bY(k) reads QL_Y + 50 MFMA + E-prefetch Y
// so MFMA/ds_read of one stream overlaps the independent VALU/ds_write of the
// other, and no post-barrier read ever depends on a just-issued write. QL is
// single-buffered per stream (write->bar->read->bar->write alternation).
// QROW=720B (180 dw == 20 mod 32): provably conflict-free b128 reads (exactly
// 8 accesses/bank) and b64 writes (4/bank). E-prefetch = one running pointer
// per stream, +ROWB per phase-b; chunk 0's negative-t reads land harmlessly in
// the Apk/Bfr region (values discarded by the exact Pa:=I reset at IW).
__global__ __launch_bounds__(256, 1)
void hmm_fused5(const uint32_t* __restrict__ Apk, const uint2* __restrict__ Efrag,
                const float* __restrict__ Ivec, float* __restrict__ out) {
  __shared__ __attribute__((aligned(16))) _Float16 QLX[16 * (QROW / 2)];
  __shared__ __attribute__((aligned(16))) _Float16 QLY[16 * (QROW / 2)];
  __shared__ float zX[16], zY[16];
  int bg = blockIdx.y, bbase = bg * 16;
  int cc0 = blockIdx.x * 2, cc1 = cc0 + 1;
  int tid = threadIdx.x, lane = tid & 63, w = tid >> 6;
  int gl = lane & 15, quad = lane >> 4;

  half8 bfA[5][10];
#pragma unroll
  for (int q = 0; q < 5; q++)
#pragma unroll
    for (int kt = 0; kt < 10; kt++)
      bfA[q][kt] = h8_from_u4(((const uint4*)Apk)[((w * 5 + q) * 10 + kt) * 64 + lane]);
#pragma unroll
  for (int q = 0; q < 5; q++)
#pragma unroll
    for (int kt = 0; kt < 10; kt++) asm volatile("" : "+v"(bfA[q][kt]));

  // P state-major: lane holds states (w*5+q)*16 + quad*4 + r for batch gl
  floatx4 PaX[5], PaY[5];
#pragma unroll
  for (int q = 0; q < 5; q++) {
    int sb = (w * 5 + q) * 16 + quad * 4;
#pragma unroll
    for (int r = 0; r < 4; r++) {
      int st = sb + r;
      PaX[q][r] = (st < S_DIM) ? ((cc0 == 0) ? Ivec[st] : 1.0f) : 0.f;
      PaY[q][r] = (st < S_DIM) ? 1.0f : 0.f;
    }
  }
  if (tid < 16) { zX[tid] = 0.f; zY[tid] = 0.f; }

  int tfX = cc0 * CHL - WARM + 1;   // -5 for cc0==0 (garbage warm, reset at IW)
  int tfY = cc1 * CHL - WARM + 1;

  // per-lane byte offset within an Efrag row
  ptrdiff_t laneoff = ((ptrdiff_t)bg * 1280 + (ptrdiff_t)(w * 5) * 64 + lane) * 8;
  const char* pX = (const char*)Efrag + (ptrdiff_t)(tfX - 1) * (ptrdiff_t)ROWB + laneoff;
  const char* pY = (const char*)Efrag + (ptrdiff_t)(tfY - 1) * (ptrdiff_t)ROWB + laneoff;

  uint2 EXa[5], EXb[5], EYa[5], EYb[5];
#pragma unroll
  for (int q = 0; q < 5; q++) EXa[q] = *(const uint2*)(pX + q * 512);
  pX += ROWB;
#pragma unroll
  for (int q = 0; q < 5; q++) EXb[q] = *(const uint2*)(pX + q * 512);
  pX += ROWB;
#pragma unroll
  for (int q = 0; q < 5; q++) EYa[q] = *(const uint2*)(pY + q * 512);
  pY += ROWB;
#pragma unroll
  for (int q = 0; q < 5; q++) EYb[q] = *(const uint2*)(pY + q * 512);
  pY += ROWB;

  const int wb = gl * QROW + w * 160 + quad * 8;   // write base (byte); +q*32
  const int rb = gl * QROW + quad * 16;            // read base (byte); +kt*64

  float llw0 = 0.f, llw1 = 0.f;

  // phase a: qv = P (.) E; optional z-checkpoint; optional QL write
  auto phA = [&](floatx4 (&Pa)[5], uint2 (&E)[5], _Float16* ql, float* zs,
                 bool zchk, bool wr) {
    float qv[5][4];
#pragma unroll
    for (int q = 0; q < 5; q++) {
      half4 ev = h4_from_u2(E[q]);
#pragma unroll
      for (int r = 0; r < 4; r++) qv[q][r] = Pa[q][r] * (float)ev[r];
    }
    if (zchk) {
      float z = 0.f;
#pragma unroll
      for (int q = 0; q < 5; q++) z += (qv[q][0] + qv[q][1]) + (qv[q][2] + qv[q][3]);
      z += __shfl_xor(z, 16); z += __shfl_xor(z, 32);
      if (lane < 16) atomicAdd(&zs[lane], z);
    }
    if (wr) {
#pragma unroll
      for (int q = 0; q < 5; q++) {
        uint2 o; o.x = pk2(qv[q][0], qv[q][1]); o.y = pk2(qv[q][2], qv[q][3]);
        *(uint2*)((char*)ql + wb + q * 32) = o;
      }
    }
  };
  // phase b: E-prefetch (running ptr) + P = A^T @ Q (10x ds_read_b128, 50 MFMA)
  auto phB = [&](floatx4 (&Pa)[5], const _Float16* ql, const char*& p, uint2 (&E)[5]) {
#pragma unroll
    for (int q = 0; q < 5; q++) E[q] = *(const uint2*)(p + q * 512);
    p += ROWB;
#pragma unroll
    for (int q = 0; q < 5; q++) Pa[q] = (floatx4){0.f, 0.f, 0.f, 0.f};
#pragma unroll
    for (int kt = 0; kt < 10; kt++) {
      half8 qf = h8_from_u4(*(const uint4*)((const char*)ql + rb + kt * 64));
#pragma unroll
      for (int q = 0; q < 5; q++)
        Pa[q] = __builtin_amdgcn_mfma_f32_16x16x32_f16(bfA[q][kt], qf, Pa[q], 0, 0, 0);
    }
  };
  auto phBnp = [&](floatx4 (&Pa)[5], const _Float16* ql) {   // tail: no prefetch
#pragma unroll
    for (int q = 0; q < 5; q++) Pa[q] = (floatx4){0.f, 0.f, 0.f, 0.f};
#pragma unroll
    for (int kt = 0; kt < 10; kt++) {
      half8 qf = h8_from_u4(*(const uint4*)((const char*)ql + rb + kt * 64));
#pragma unroll
      for (int q = 0; q < 5; q++)
        Pa[q] = __builtin_amdgcn_mfma_f32_16x16x32_f16(bfA[q][kt], qf, Pa[q], 0, 0, 0);
    }
  };

  // half 0: aX(0)
  phA(PaX, EXa, QLX, zX, false, true);
  __syncthreads();

  for (int kk = 0; kk < NSTEP - 1; kk += 2) {
    // HALF_A(kk): bX(kk) [fills EXa] || aY(kk) [uses EYa]
    phB(PaX, QLX, pX, EXa);
    phA(PaY, EYa, QLY, zY, false, true);
    __syncthreads();
    // HALF_B(kk): bY(kk) [fills EYa] || aX(kk+1) [uses EXb; z if kk+1==IW]
    phB(PaY, QLY, pY, EYa);
    phA(PaX, EXb, QLX, zX, (kk + 1 == IW), true);
    __syncthreads();
    // HALF_A(kk+1): (llw0 read) bX(kk+1) [fills EXb] (+reset) || aY(kk+1) [EYb]
    if (kk + 1 == IW && tid < 16) { llw0 = cc0 ? logf(zX[tid]) : 0.f; zX[tid] = 0.f; }
    phB(PaX, QLX, pX, EXb);
    if (kk + 1 == IW && cc0 == 0) {
      // exact restart of chunk 0 at t=0 (its next phase-a uses E(0))
#pragma unroll
      for (int q = 0; q < 5; q++) {
        int sb = (w * 5 + q) * 16 + quad * 4;
#pragma unroll
        for (int r = 0; r < 4; r++) {
          int st = sb + r;
          PaX[q][r] = (st < S_DIM) ? Ivec[st] : 0.f;
        }
      }
    }
    phA(PaY, EYb, QLY, zY, (kk + 1 == IW), true);
    __syncthreads();
    // HALF_B(kk+1): (llw1 read) bY(kk+1) [fills EYb] || aX(kk+2) [uses EXa]
    if (kk + 1 == IW && tid < 16) { llw1 = logf(zY[tid]); zY[tid] = 0.f; }
    phB(PaY, QLY, pY, EYb);
    phA(PaX, EXa, QLX, zX, false, true);
    __syncthreads();
  }
  // tail k = NSTEP-1 = 20 (even):
  phBnp(PaX, QLX);                       // bX(20); prefetch target never consumed
  phA(PaY, EYa, QLY, zY, false, true);   // aY(20)
  __syncthreads();
  phBnp(PaY, QLY);                       // bY(20)
  phA(PaX, EXb, QLX, zX, true, false);   // aX(21) = final-z X, no QL write
  __syncthreads();
  phA(PaY, EYb, QLY, zY, true, false);   // aY(21) = final-z Y
  __syncthreads();

  if (tid < 16) {
    float v = (logf(zX[tid]) - llw0) + (logf(zY[tid]) - llw1)
              - 2.0f * (float)CHL * LN128;   // CHL accounted x128 steps per stream
    atomicAdd(&out[bbase + tid], v);
  }
}

// ---- fallback (inp-direct, no Efrag workspace) ----
__global__ __launch_bounds__(640, 3)
void hmm_fused(const uint32_t* __restrict__ Apk,
               const uint32_t* __restrict__ Bfr,
               const float* __restrict__ inp,
               const float* __restrict__ Ivec,
               float* __restrict__ out) {
  __shared__ __attribute__((aligned(16))) _Float16 inH[2][16 * 136];
  __shared__ __attribute__((aligned(16))) _Float16 QLf[2][16 * 336];
  __shared__ float zslot[16];
  int c = blockIdx.x, bbase = blockIdx.y * 16;
  int tid = threadIdx.x, lane = tid & 63, w = tid >> 6;
  int gl = lane & 15, quad = lane >> 4;

  half8 bfA[2][10], bfB[2][4];
#pragma unroll
  for (int q = 0; q < 2; q++) {
#pragma unroll
    for (int kt = 0; kt < 10; kt++)
      bfA[q][kt] = h8_from_u4(((const uint4*)Apk)[((w * 2 + q) * 10 + kt) * 64 + lane]);
#pragma unroll
    for (int kt = 0; kt < 4; kt++)
      bfB[q][kt] = h8_from_u4(((const uint4*)Bfr)[((w * 2 + q) * 4 + kt) * 64 + lane]);
  }
#pragma unroll
  for (int q = 0; q < 2; q++) {
#pragma unroll
    for (int kt = 0; kt < 10; kt++) asm volatile("" : "+v"(bfA[q][kt]));
#pragma unroll
    for (int kt = 0; kt < 4; kt++)  asm volatile("" : "+v"(bfB[q][kt]));
  }

  float Pa[2][4];
#pragma unroll
  for (int q = 0; q < 2; q++) {
    int n = (w * 2 + q) * 16 + gl;
    float v = (n < S_DIM) ? (c == 0 ? Ivec[n] : 1.0f) : 0.f;
#pragma unroll
    for (int r = 0; r < 4; r++) Pa[q][r] = v;
  }
  if (tid < 16) zslot[tid] = 0.f;

  int t_first = (c == 0) ? 1 : (c * CHL - WARM + 1);
  int nstep   = (c == 0) ? (CHL - 1) : (CHL + WARM - 1);
  int iw      = (c == 0) ? -1 : (WARM - 1);
  int t_last  = t_first - 1 + nstep;

  {
    int t0 = t_first - 1;
#pragma unroll
    for (int s = 0; s < 2; s++) {
      int flat = tid + s * 640;
      if (flat < 1024) {
        int r = flat >> 6, c2 = flat & 63;
        float2 v; v.x = 0.f; v.y = 0.f;
        if (c2 < 63) v = *(const float2*)(inp + ((size_t)(bbase + r) * T_LEN + t0) * E_DIM + 2 * c2);
        *(uint32_t*)&inH[0][r * 136 + 2 * c2] = pk2(v.x, v.y);
      }
    }
  }
  float2 g[2];
#pragma unroll
  for (int s = 0; s < 2; s++) {
    int flat = tid + s * 640;
    g[s].x = 0.f; g[s].y = 0.f;
    if (flat < 1024) {
      int r = flat >> 6, c2 = flat & 63;
      if (c2 < 63) g[s] = *(const float2*)(inp + ((size_t)(bbase + r) * T_LEN + t_first) * E_DIM + 2 * c2);
    }
  }
  float llw = 0.f;
  __syncthreads();

  for (int i = 0; i <= nstep; i++) {
    int cur = i & 1, nxt = cur ^ 1;
    floatx4 Ea0 = (floatx4){0.f, 0.f, 0.f, 0.f};
    floatx4 Ea1 = (floatx4){0.f, 0.f, 0.f, 0.f};
#pragma unroll
    for (int kt = 0; kt < 4; kt++) {
      half8 af = h8_from_u4(*(const uint4*)&inH[cur][gl * 136 + kt * 32 + quad * 8]);
      Ea0 = __builtin_amdgcn_mfma_f32_16x16x32_f16(af, bfB[0][kt], Ea0, 0, 0, 0);
      Ea1 = __builtin_amdgcn_mfma_f32_16x16x32_f16(af, bfB[1][kt], Ea1, 0, 0, 0);
    }
    float qv[2][4];
#pragma unroll
    for (int r = 0; r < 4; r++) { qv[0][r] = Pa[0][r] * Ea0[r]; qv[1][r] = Pa[1][r] * Ea1[r]; }
    if (i == iw || i == nstep) {
      float s0 = qv[0][0] + qv[1][0], s1 = qv[0][1] + qv[1][1];
      float s2 = qv[0][2] + qv[1][2], s3 = qv[0][3] + qv[1][3];
#pragma unroll
      for (int off = 1; off <= 8; off <<= 1) {
        s0 += __shfl_xor(s0, off); s1 += __shfl_xor(s1, off);
        s2 += __shfl_xor(s2, off); s3 += __shfl_xor(s3, off);
      }
      if (gl == 0) {
        atomicAdd(&zslot[quad * 4 + 0], s0);
        atomicAdd(&zslot[quad * 4 + 1], s1);
        atomicAdd(&zslot[quad * 4 + 2], s2);
        atomicAdd(&zslot[quad * 4 + 3], s3);
      }
    }
#pragma unroll
    for (int q = 0; q < 2; q++) {
      int k = (w * 2 + q) * 16 + gl;
#pragma unroll
      for (int r = 0; r < 4; r++)
        QLf[cur][(quad * 4 + r) * 336 + k] = (_Float16)qv[q][r];
    }
    if (i < nstep) {
#pragma unroll
      for (int s = 0; s < 2; s++) {
        int flat = tid + s * 640;
        if (flat < 1024) {
          int r = flat >> 6, c2 = flat & 63;
          uint32_t pv = (c2 < 63) ? pk2(g[s].x, g[s].y) : 0u;
          *(uint32_t*)&inH[nxt][r * 136 + 2 * c2] = pv;
        }
      }
    }
    __syncthreads();
    if (i == iw && tid < 16) { llw = logf(zslot[tid]); zslot[tid] = 0.f; }
    if (i == nstep) {
      if (tid < 16) {
        float lle = logf(zslot[tid]);
        atomicAdd(&out[bbase + tid], lle - llw - (float)CHL * LN128);
      }
      break;
    }
    {
      int tp = t_first + i + 1; if (tp > t_last) tp = t_last;
#pragma unroll
      for (int s = 0; s < 2; s++) {
        int flat = tid + s * 640;
        g[s].x = 0.f; g[s].y = 0.f;
        if (flat < 1024) {
          int r = flat >> 6, c2 = flat & 63;
          if (c2 < 63) g[s] = *(const float2*)(inp + ((size_t)(bbase + r) * T_LEN + tp) * E_DIM + 2 * c2);
        }
      }
    }
    floatx4 acc0 = (floatx4){0.f, 0.f, 0.f, 0.f};
    floatx4 acc1 = (floatx4){0.f, 0.f, 0.f, 0.f};
#pragma unroll
    for (int kt = 0; kt < 10; kt++) {
      half8 afv = h8_from_u4(*(const uint4*)&QLf[cur][gl * 336 + kt * 32 + quad * 8]);
      acc0 = __builtin_amdgcn_mfma_f32_16x16x32_f16(afv, bfA[0][kt], acc0, 0, 0, 0);
      acc1 = __builtin_amdgcn_mfma_f32_16x16x32_f16(afv, bfA[1][kt], acc1, 0, 0, 0);
    }
#pragma unroll
    for (int r = 0; r < 4; r++) { Pa[0][r] = acc0[r]; Pa[1][r] = acc1[r]; }
  }
}

extern "C" void kernel_launch(void* const* d_in, const int* in_sizes, int n_in,
                              void* d_out, int out_size, void* d_ws, size_t ws_size,
                              hipStream_t stream) {
  const float* inp = (const float*)d_in[0];   // [32,4096,126]
  const float* A   = (const float*)d_in[1];   // [308,308]
  const float* Bm  = (const float*)d_in[2];   // [308,126]
  const float* Iv  = (const float*)d_in[3];   // [308]
  float* out = (float*)d_out;                 // [32]

  uint8_t* ws = (uint8_t*)d_ws;
  uint32_t* Apk = (uint32_t*)(ws);                 // 200 KiB
  uint32_t* Bfr = (uint32_t*)(ws + (256u << 10));  // 80 KiB
  const size_t EOFF   = (size_t)384 << 10;
  const size_t EBYTES = (size_t)T_LEN * ROWB;      // 80 MiB (rows t = 0..4095)

  hipLaunchKernelGGL(init_pack, dim3(71), dim3(256), 0, stream, A, Bm, Apk, Bfr, out);
  if (ws_size >= EOFF + EBYTES) {
    uint2* Efrag = (uint2*)(ws + EOFF);
    hipLaunchKernelGGL(emis_pack, dim3(T_LEN / TC, 2), dim3(256), 0, stream, Bfr, inp, Efrag);
    hipLaunchKernelGGL(hmm_fused5, dim3(NCH / 2, NBATCH / 16), dim3(256), 0, stream,
                       Apk, Efrag, Iv, out);
  } else {
    hipLaunchKernelGGL(hmm_fused, dim3(NCH, NBATCH / 16), dim3(640), 0, stream,
                       Apk, Bfr, inp, Iv, out);
  }
}